// Round 1
// baseline (350.012 us; speedup 1.0000x reference)
//
#include <hip/hip_runtime.h>

#define B_ 2048
#define P_ 32
#define Q_ 65
#define O_ 16
#define H_ 32

#define PCHUNK 8   // p's per block in stage 1  (P_/PCHUNK blocks along p)
#define QCHUNK 5   // q's per block in stage 2  (Q_/QCHUNK blocks along q)
#define ILP 2      // batch elements per thread

// tanh(x) = 1 - 2/(exp(2x)+1); v_exp_f32 + v_rcp_f32 path, ~1e-6 abs err,
// saturates to +/-1 for large |x| (exp->inf => rcp->0 ; exp->0 => 1-2=-1).
__device__ __forceinline__ float fast_tanh(float v) {
    float e = __expf(2.0f * v);
    return 1.0f - 2.0f * __builtin_amdgcn_rcpf(e + 1.0f);
}

// Stage 1: s[b,q] = sum_p psi_{p,q}(x[b,p])
// grid.x = Q_ * (P_/PCHUNK), grid.y = B_/(256*ILP), block = 256
__global__ __launch_bounds__(256) void psi_kernel(
    const float* __restrict__ x,    // [B,P]
    const float* __restrict__ w1,   // [P,Q,H]
    const float* __restrict__ b1,   // [P,Q,H]
    const float* __restrict__ w2,   // [P,Q,H,H]
    const float* __restrict__ b2,   // [P,Q,H]
    const float* __restrict__ w3,   // [P,Q,H]
    const float* __restrict__ b3,   // [P,Q]
    float* __restrict__ s)          // [B,Q] accumulated
{
    const int gx = blockIdx.x;
    const int q  = gx / (P_ / PCHUNK);
    const int p0 = (gx % (P_ / PCHUNK)) * PCHUNK;
    const int b  = blockIdx.y * (256 * ILP) + threadIdx.x;

    float sum0 = 0.0f, sum1 = 0.0f;

    for (int pi = 0; pi < PCHUNK; ++pi) {
        const int p  = p0 + pi;
        const int pq = p * Q_ + q;                 // block-uniform
        const float* __restrict__ W1  = w1 + pq * H_;
        const float* __restrict__ Bv1 = b1 + pq * H_;
        const float* __restrict__ W2  = w2 + pq * (H_ * H_);
        const float* __restrict__ Bv2 = b2 + pq * H_;
        const float* __restrict__ W3  = w3 + pq * H_;
        const float  Bv3 = b3[pq];

        const float xv0 = x[(b)       * P_ + p];
        const float xv1 = x[(b + 256) * P_ + p];

        float acc0[H_], acc1[H_];
        #pragma unroll
        for (int k = 0; k < H_; ++k) {
            const float bb = Bv2[k];
            acc0[k] = bb; acc1[k] = bb;
        }

        #pragma unroll 4
        for (int h = 0; h < H_; ++h) {
            const float w1h = W1[h];
            const float b1h = Bv1[h];
            const float h10 = fast_tanh(fmaf(xv0, w1h, b1h));
            const float h11 = fast_tanh(fmaf(xv1, w1h, b1h));
            const float* __restrict__ row = W2 + h * H_;
            #pragma unroll
            for (int k = 0; k < H_; ++k) {
                const float w = row[k];
                acc0[k] = fmaf(h10, w, acc0[k]);
                acc1[k] = fmaf(h11, w, acc1[k]);
            }
        }

        float ps0 = Bv3, ps1 = Bv3;
        #pragma unroll
        for (int k = 0; k < H_; ++k) {
            const float w = W3[k];
            ps0 = fmaf(fast_tanh(acc0[k]), w, ps0);
            ps1 = fmaf(fast_tanh(acc1[k]), w, ps1);
        }
        sum0 += ps0; sum1 += ps1;
    }

    atomicAdd(&s[(b)       * Q_ + q], sum0);
    atomicAdd(&s[(b + 256) * Q_ + q], sum1);
}

// Stage 2: out[b,o] = sum_q phi_{q,o}(s[b,q])
// grid.x = O_ * (Q_/QCHUNK), grid.y = B_/(256*ILP), block = 256
__global__ __launch_bounds__(256) void phi_kernel(
    const float* __restrict__ s,    // [B,Q]
    const float* __restrict__ w1,   // [Q,O,H]
    const float* __restrict__ b1,   // [Q,O,H]
    const float* __restrict__ w2,   // [Q,O,H,H]
    const float* __restrict__ b2,   // [Q,O,H]
    const float* __restrict__ w3,   // [Q,O,H]
    const float* __restrict__ b3,   // [Q,O]
    float* __restrict__ out)        // [B,O] accumulated
{
    const int gx = blockIdx.x;
    const int o  = gx / (Q_ / QCHUNK);
    const int q0 = (gx % (Q_ / QCHUNK)) * QCHUNK;
    const int b  = blockIdx.y * (256 * ILP) + threadIdx.x;

    float sum0 = 0.0f, sum1 = 0.0f;

    for (int qi = 0; qi < QCHUNK; ++qi) {
        const int q  = q0 + qi;
        const int qo = q * O_ + o;                 // block-uniform
        const float* __restrict__ W1  = w1 + qo * H_;
        const float* __restrict__ Bv1 = b1 + qo * H_;
        const float* __restrict__ W2  = w2 + qo * (H_ * H_);
        const float* __restrict__ Bv2 = b2 + qo * H_;
        const float* __restrict__ W3  = w3 + qo * H_;
        const float  Bv3 = b3[qo];

        const float sv0 = s[(b)       * Q_ + q];
        const float sv1 = s[(b + 256) * Q_ + q];

        float acc0[H_], acc1[H_];
        #pragma unroll
        for (int k = 0; k < H_; ++k) {
            const float bb = Bv2[k];
            acc0[k] = bb; acc1[k] = bb;
        }

        #pragma unroll 4
        for (int h = 0; h < H_; ++h) {
            const float w1h = W1[h];
            const float b1h = Bv1[h];
            const float g10 = fast_tanh(fmaf(sv0, w1h, b1h));
            const float g11 = fast_tanh(fmaf(sv1, w1h, b1h));
            const float* __restrict__ row = W2 + h * H_;
            #pragma unroll
            for (int k = 0; k < H_; ++k) {
                const float w = row[k];
                acc0[k] = fmaf(g10, w, acc0[k]);
                acc1[k] = fmaf(g11, w, acc1[k]);
            }
        }

        float ph0 = Bv3, ph1 = Bv3;
        #pragma unroll
        for (int k = 0; k < H_; ++k) {
            const float w = W3[k];
            ph0 = fmaf(fast_tanh(acc0[k]), w, ph0);
            ph1 = fmaf(fast_tanh(acc1[k]), w, ph1);
        }
        sum0 += ph0; sum1 += ph1;
    }

    atomicAdd(&out[(b)       * O_ + o], sum0);
    atomicAdd(&out[(b + 256) * O_ + o], sum1);
}

extern "C" void kernel_launch(void* const* d_in, const int* in_sizes, int n_in,
                              void* d_out, int out_size, void* d_ws, size_t ws_size,
                              hipStream_t stream) {
    const float* x      = (const float*)d_in[0];
    const float* psi_w1 = (const float*)d_in[1];
    const float* psi_b1 = (const float*)d_in[2];
    const float* psi_w2 = (const float*)d_in[3];
    const float* psi_b2 = (const float*)d_in[4];
    const float* psi_w3 = (const float*)d_in[5];
    const float* psi_b3 = (const float*)d_in[6];
    const float* phi_w1 = (const float*)d_in[7];
    const float* phi_b1 = (const float*)d_in[8];
    const float* phi_w2 = (const float*)d_in[9];
    const float* phi_b2 = (const float*)d_in[10];
    const float* phi_w3 = (const float*)d_in[11];
    const float* phi_b3 = (const float*)d_in[12];

    float* out = (float*)d_out;
    float* s   = (float*)d_ws;   // [B,Q] intermediate

    hipMemsetAsync(s, 0, (size_t)B_ * Q_ * sizeof(float), stream);
    hipMemsetAsync(out, 0, (size_t)B_ * O_ * sizeof(float), stream);

    dim3 g1(Q_ * (P_ / PCHUNK), B_ / (256 * ILP));
    psi_kernel<<<g1, 256, 0, stream>>>(x, psi_w1, psi_b1, psi_w2, psi_b2,
                                       psi_w3, psi_b3, s);

    dim3 g2(O_ * (Q_ / QCHUNK), B_ / (256 * ILP));
    phi_kernel<<<g2, 256, 0, stream>>>(s, phi_w1, phi_b1, phi_w2, phi_b2,
                                       phi_w3, phi_b3, out);
}

// Round 3
// 291.671 us; speedup vs baseline: 1.2000x; 1.2000x over previous
//
#include <hip/hip_runtime.h>
#include <hip/hip_bf16.h>

#define B_ 2048
#define P_ 32
#define Q_ 65
#define O_ 16
#define H_ 32

typedef __attribute__((ext_vector_type(8))) short short8;
typedef __attribute__((ext_vector_type(4))) float f32x4;

union F4S8 { float4 f; short8 s; };

// tanh(x) = 1 - 2/(exp(2x)+1); saturates correctly at +/-inf, ~1e-6 abs err.
__device__ __forceinline__ float fast_tanh(float v) {
    float e = __expf(2.0f * v);
    return 1.0f - 2.0f * __builtin_amdgcn_rcpf(e + 1.0f);
}

__device__ __forceinline__ unsigned short bf_rne(float f) {
    unsigned u = __float_as_uint(f);
    return (unsigned short)((u + 0x7FFFu + ((u >> 16) & 1u)) >> 16);
}

// ---------------------------------------------------------------------------
// Prep: repack W2[pq][32][32] fp32 into per-lane MFMA B-fragments, hi/lo bf16.
// Layout per (pq,lane): [t0hi 16B][t0lo 16B][t1hi 16B][t1lo 16B] = 64B.
// Slot (lane,j) holds W2[h][col] with h = (lane>>4)*8 + j, col = (lane&15)+16t.
// ---------------------------------------------------------------------------
__global__ __launch_bounds__(256)
void prep_frag(const float* __restrict__ w2, float* __restrict__ frag, int npairs)
{
    int idx = blockIdx.x * 256 + threadIdx.x;
    if (idx >= npairs * 64) return;
    int pq = idx >> 6, lane = idx & 63;
    int g = lane >> 4, col = lane & 15;
    const float* Wp = w2 + (size_t)pq * (H_ * H_);

    short8 h0v, l0v, h1v, l1v;
    #pragma unroll
    for (int j = 0; j < 8; ++j) {
        float v0 = Wp[(g * 8 + j) * H_ + col];
        float v1 = Wp[(g * 8 + j) * H_ + 16 + col];
        unsigned short hb0 = bf_rne(v0);
        h0v[j] = (short)hb0;
        l0v[j] = (short)bf_rne(v0 - __uint_as_float(((unsigned)hb0) << 16));
        unsigned short hb1 = bf_rne(v1);
        h1v[j] = (short)hb1;
        l1v[j] = (short)bf_rne(v1 - __uint_as_float(((unsigned)hb1) << 16));
    }
    F4S8 a, b, c, d; a.s = h0v; b.s = l0v; c.s = h1v; d.s = l1v;
    float4* op = reinterpret_cast<float4*>(frag + (size_t)idx * 16);
    op[0] = a.f; op[1] = b.f; op[2] = c.f; op[3] = d.f;
}

// ---------------------------------------------------------------------------
// One tiny-MLP evaluation step for 16 batch rows per wave (rows = lane&15),
// accumulating layer-3 partials (per-lane, per-k) into psum[4].
// ---------------------------------------------------------------------------
template<bool PREP>
__device__ __forceinline__ void eval_mlp(
    const float* __restrict__ w1p,    // w1 + pq*H + g*8
    const float* __restrict__ b1p,    // b1 + pq*H + g*8
    const float* __restrict__ w2p,    // w2 + pq*H*H           (gather path)
    const float* __restrict__ fragp,  // frag + (pq*64+lane)*16 (prep path)
    float b2t0, float b2t1, float w3t0, float w3t1,
    float xv, int g, int col,
    float psum[4])
{
    float w1v[8], b1v[8];
    *reinterpret_cast<float4*>(&w1v[0]) = *reinterpret_cast<const float4*>(w1p);
    *reinterpret_cast<float4*>(&w1v[4]) = *reinterpret_cast<const float4*>(w1p + 4);
    *reinterpret_cast<float4*>(&b1v[0]) = *reinterpret_cast<const float4*>(b1p);
    *reinterpret_cast<float4*>(&b1v[4]) = *reinterpret_cast<const float4*>(b1p + 4);

    // layer 1 + tanh, then hi/lo bf16 split of activations (trunc hi, exact lo)
    short8 ahi, alo;
    #pragma unroll
    for (int j = 0; j < 8; ++j) {
        float t = fast_tanh(fmaf(xv, w1v[j], b1v[j]));
        unsigned u = __float_as_uint(t);
        ahi[j] = (short)(u >> 16);
        float lo = t - __uint_as_float(u & 0xFFFF0000u);
        alo[j] = (short)(__float_as_uint(lo) >> 16);
    }

    F4S8 u0, u1, u2, u3;
    if (PREP) {
        const float4* fp = reinterpret_cast<const float4*>(fragp);
        u0.f = fp[0]; u1.f = fp[1]; u2.f = fp[2]; u3.f = fp[3];
    } else {
        #pragma unroll
        for (int j = 0; j < 8; ++j) {
            float v0 = w2p[(g * 8 + j) * H_ + col];
            float v1 = w2p[(g * 8 + j) * H_ + 16 + col];
            unsigned q0 = __float_as_uint(v0);
            u0.s[j] = (short)(q0 >> 16);
            u1.s[j] = (short)(__float_as_uint(v0 - __uint_as_float(q0 & 0xFFFF0000u)) >> 16);
            unsigned q1 = __float_as_uint(v1);
            u2.s[j] = (short)(q1 >> 16);
            u3.s[j] = (short)(__float_as_uint(v1 - __uint_as_float(q1 & 0xFFFF0000u)) >> 16);
        }
    }

    // layer 2: [16x32]·[32x32] via 2 col-tiles × 3 MFMA (hi/lo compensation)
    f32x4 acc0 = {b2t0, b2t0, b2t0, b2t0};
    f32x4 acc1 = {b2t1, b2t1, b2t1, b2t1};
    acc0 = __builtin_amdgcn_mfma_f32_16x16x32_bf16(ahi, u0.s, acc0, 0, 0, 0);
    acc0 = __builtin_amdgcn_mfma_f32_16x16x32_bf16(alo, u0.s, acc0, 0, 0, 0);
    acc0 = __builtin_amdgcn_mfma_f32_16x16x32_bf16(ahi, u1.s, acc0, 0, 0, 0);
    acc1 = __builtin_amdgcn_mfma_f32_16x16x32_bf16(ahi, u2.s, acc1, 0, 0, 0);
    acc1 = __builtin_amdgcn_mfma_f32_16x16x32_bf16(alo, u2.s, acc1, 0, 0, 0);
    acc1 = __builtin_amdgcn_mfma_f32_16x16x32_bf16(ahi, u3.s, acc1, 0, 0, 0);

    // layer 2 tanh + layer 3 partial (per-lane k = col and col+16)
    #pragma unroll
    for (int r = 0; r < 4; ++r) {
        psum[r] = fmaf(fast_tanh(acc0[r]), w3t0, psum[r]);
        psum[r] = fmaf(fast_tanh(acc1[r]), w3t1, psum[r]);
    }
}

// ---------------------------------------------------------------------------
// Stage 1: sT[q][b] = sum_p psi_{p,q}(x[b,p]).  grid = (Q, B/64), block 256.
// Each wave owns 16 batch rows; p-loop accumulates in registers; one plain
// store per (row,q) — no atomics, no zeroing of sT needed.
// ---------------------------------------------------------------------------
template<bool PREP>
__global__ __launch_bounds__(256)
void psi_main(const float* __restrict__ x,
              const float* __restrict__ w1, const float* __restrict__ b1,
              const float* __restrict__ w2, const float* __restrict__ b2,
              const float* __restrict__ w3, const float* __restrict__ b3,
              const float* __restrict__ frag, float* __restrict__ sT)
{
    const int q = blockIdx.x;
    const int btile = blockIdx.y;
    const int lane = threadIdx.x & 63;
    const int wid = threadIdx.x >> 6;
    const int g = lane >> 4, col = lane & 15;
    const int b0w = btile * 64 + wid * 16;

    float psum[4] = {0.f, 0.f, 0.f, 0.f};
    float b3sum = 0.f;

    for (int p = 0; p < P_; ++p) {
        const int pq = p * Q_ + q;
        const float xv = x[(size_t)(b0w + col) * P_ + p];
        const float b2t0 = b2[pq * H_ + col];
        const float b2t1 = b2[pq * H_ + 16 + col];
        const float w3t0 = w3[pq * H_ + col];
        const float w3t1 = w3[pq * H_ + 16 + col];
        b3sum += b3[pq];
        eval_mlp<PREP>(w1 + pq * H_ + g * 8, b1 + pq * H_ + g * 8,
                       w2 + (size_t)pq * (H_ * H_),
                       frag + ((size_t)pq * 64 + lane) * 16,
                       b2t0, b2t1, w3t0, w3t1, xv, g, col, psum);
    }

    // reduce over k (low 4 lane bits); rows live at (g*4 + reg)
    #pragma unroll
    for (int r = 0; r < 4; ++r) {
        psum[r] += __shfl_xor(psum[r], 1);
        psum[r] += __shfl_xor(psum[r], 2);
        psum[r] += __shfl_xor(psum[r], 4);
        psum[r] += __shfl_xor(psum[r], 8);
    }
    float v01 = (lane & 1) ? psum[1] : psum[0];
    float v23 = (lane & 1) ? psum[3] : psum[2];
    float v = (lane & 2) ? v23 : v01;
    if ((lane & 15) < 4) {
        int row = b0w + g * 4 + (lane & 3);
        sT[(size_t)q * B_ + row] = v + b3sum;
    }
}

// ---------------------------------------------------------------------------
// Stage 2: out[b][o] += sum_{q in group} phi_{q,o}(sT[q][b]).
// grid = (O, 5, B/64), 13 q's per block; atomicAdd into zeroed out.
// ---------------------------------------------------------------------------
template<bool PREP>
__global__ __launch_bounds__(256)
void phi_main(const float* __restrict__ sT,
              const float* __restrict__ w1, const float* __restrict__ b1,
              const float* __restrict__ w2, const float* __restrict__ b2,
              const float* __restrict__ w3, const float* __restrict__ b3,
              const float* __restrict__ frag, float* __restrict__ out)
{
    const int o = blockIdx.x;
    const int qg = blockIdx.y;
    const int btile = blockIdx.z;
    const int lane = threadIdx.x & 63;
    const int wid = threadIdx.x >> 6;
    const int g = lane >> 4, col = lane & 15;
    const int b0w = btile * 64 + wid * 16;

    float psum[4] = {0.f, 0.f, 0.f, 0.f};
    float b3sum = 0.f;

    for (int i = 0; i < 13; ++i) {
        const int qq = qg * 13 + i;
        const int qo = qq * O_ + o;
        const float sv = sT[(size_t)qq * B_ + b0w + col];
        const float b2t0 = b2[qo * H_ + col];
        const float b2t1 = b2[qo * H_ + 16 + col];
        const float w3t0 = w3[qo * H_ + col];
        const float w3t1 = w3[qo * H_ + 16 + col];
        b3sum += b3[qo];
        eval_mlp<PREP>(w1 + qo * H_ + g * 8, b1 + qo * H_ + g * 8,
                       w2 + (size_t)qo * (H_ * H_),
                       frag + ((size_t)qo * 64 + lane) * 16,
                       b2t0, b2t1, w3t0, w3t1, sv, g, col, psum);
    }

    #pragma unroll
    for (int r = 0; r < 4; ++r) {
        psum[r] += __shfl_xor(psum[r], 1);
        psum[r] += __shfl_xor(psum[r], 2);
        psum[r] += __shfl_xor(psum[r], 4);
        psum[r] += __shfl_xor(psum[r], 8);
    }
    float v01 = (lane & 1) ? psum[1] : psum[0];
    float v23 = (lane & 1) ? psum[3] : psum[2];
    float v = (lane & 2) ? v23 : v01;
    if ((lane & 15) < 4) {
        int row = b0w + g * 4 + (lane & 3);
        atomicAdd(&out[(size_t)row * O_ + o], v + b3sum);
    }
}

extern "C" void kernel_launch(void* const* d_in, const int* in_sizes, int n_in,
                              void* d_out, int out_size, void* d_ws, size_t ws_size,
                              hipStream_t stream) {
    const float* x      = (const float*)d_in[0];
    const float* psi_w1 = (const float*)d_in[1];
    const float* psi_b1 = (const float*)d_in[2];
    const float* psi_w2 = (const float*)d_in[3];
    const float* psi_b2 = (const float*)d_in[4];
    const float* psi_w3 = (const float*)d_in[5];
    const float* psi_b3 = (const float*)d_in[6];
    const float* phi_w1 = (const float*)d_in[7];
    const float* phi_b1 = (const float*)d_in[8];
    const float* phi_w2 = (const float*)d_in[9];
    const float* phi_b2 = (const float*)d_in[10];
    const float* phi_w3 = (const float*)d_in[11];
    const float* phi_b3 = (const float*)d_in[12];
    float* out = (float*)d_out;

    const size_t ST_BYTES  = (size_t)B_ * Q_ * sizeof(float);          // 532,480
    const size_t PSI_FRAGB = (size_t)P_ * Q_ * 64 * 64;                // 8,519,680
    const size_t PHI_FRAGB = (size_t)Q_ * O_ * 64 * 64;                // 4,259,840
    float* sT       = (float*)d_ws;
    float* psi_frag = (float*)((char*)d_ws + ST_BYTES);
    float* phi_frag = (float*)((char*)d_ws + ST_BYTES + PSI_FRAGB);
    const bool prep = ws_size >= ST_BYTES + PSI_FRAGB + PHI_FRAGB;

    hipMemsetAsync(out, 0, (size_t)B_ * O_ * sizeof(float), stream);

    if (prep) {
        prep_frag<<<(P_ * Q_ * 64) / 256, 256, 0, stream>>>(psi_w2, psi_frag, P_ * Q_);
        prep_frag<<<(Q_ * O_ * 64) / 256, 256, 0, stream>>>(phi_w2, phi_frag, Q_ * O_);
        psi_main<true><<<dim3(Q_, B_ / 64), 256, 0, stream>>>(
            x, psi_w1, psi_b1, psi_w2, psi_b2, psi_w3, psi_b3, psi_frag, sT);
        phi_main<true><<<dim3(O_, 5, B_ / 64), 256, 0, stream>>>(
            sT, phi_w1, phi_b1, phi_w2, phi_b2, phi_w3, phi_b3, phi_frag, out);
    } else {
        psi_main<false><<<dim3(Q_, B_ / 64), 256, 0, stream>>>(
            x, psi_w1, psi_b1, psi_w2, psi_b2, psi_w3, psi_b3, sT, sT);
        phi_main<false><<<dim3(O_, 5, B_ / 64), 256, 0, stream>>>(
            sT, phi_w1, phi_b1, phi_w2, phi_b2, phi_w3, phi_b3, sT, out);
    }
}